// Round 4
// baseline (295.770 us; speedup 1.0000x reference)
//
#include <hip/hip_runtime.h>

// MHA fwd: B=4 S=2048 D=1024 H=16 HD=64. fp32 in/out, bf16 MFMA compute.
// R4: flash Bc=128 with double-buffered K/V staging (one barrier/iter, near-free
// vmcnt drain) and split-half Vs (2x 64x64, R2's proven conflict-free layout);
// GEMM reverted to R2 merged form (unswapped epilogue, fused V-transpose).

typedef unsigned short u16;
typedef __attribute__((ext_vector_type(4))) float f32x4;
typedef __attribute__((ext_vector_type(8))) short s16x8;
typedef __attribute__((ext_vector_type(4))) unsigned short u16x4;
typedef __attribute__((ext_vector_type(2))) unsigned int u32x2;
typedef __attribute__((ext_vector_type(4))) unsigned int u32x4;

#define DEV __device__ __forceinline__

#if __has_builtin(__builtin_amdgcn_exp2f)
#define EXP2(x) __builtin_amdgcn_exp2f(x)
#else
#define EXP2(x) exp2f(x)
#endif

DEV u16 f2b(float f) {  // fp32 -> bf16 RNE
  unsigned u = __float_as_uint(f);
  u += 0x7fffu + ((u >> 16) & 1u);
  return (u16)(u >> 16);
}

DEV unsigned pack2(float a, float b) {  // two fp32 -> packed bf16x2
#if __has_builtin(__builtin_amdgcn_cvt_pk_bf16_f32)
  typedef __attribute__((ext_vector_type(2))) __bf16 bf16x2;
  bf16x2 r = __builtin_amdgcn_cvt_pk_bf16_f32(a, b);
  return __builtin_bit_cast(unsigned, r);
#else
  return (unsigned)f2b(a) | ((unsigned)f2b(b) << 16);
#endif
}

DEV void async16(const void* g, void* l) {  // 16B global -> LDS direct
  __builtin_amdgcn_global_load_lds(
      (const __attribute__((address_space(1))) unsigned int*)g,
      (__attribute__((address_space(3))) unsigned int*)l, 16, 0, 0);
}

// ---------------- cast x -> bf16 ----------------
__global__ void k_cast(const float* __restrict__ x, u16* __restrict__ xb) {
  int i = (blockIdx.x * 256 + threadIdx.x) * 4;
  float4 v = *(const float4*)(x + i);
  u16x4 o;
  o.x = f2b(v.x); o.y = f2b(v.y); o.z = f2b(v.z); o.w = f2b(v.w);
  *(u16x4*)(xb + i) = o;
}

// ---------------- transpose+convert all 4 weights (1024x1024) -> Bt bf16 ----------------
__global__ void k_packw_all(const float* __restrict__ Wq, const float* __restrict__ Wk,
                            const float* __restrict__ Wv, const float* __restrict__ Wo,
                            u16* __restrict__ wt, u16* __restrict__ wot, float qscale) {
  const float* src; u16* dst; float scale = 1.0f;
  switch (blockIdx.z) {
    case 0: src = Wq; dst = wt; scale = qscale; break;
    case 1: src = Wk; dst = wt + 1024 * 1024; break;
    case 2: src = Wv; dst = wt + 2 * 1024 * 1024; break;
    default: src = Wo; dst = wot; break;
  }
  __shared__ float tile[32][33];
  int t = threadIdx.x;
  int k0 = blockIdx.x * 32, n0 = blockIdx.y * 32;
  int c = t & 31, r0 = t >> 5;
#pragma unroll
  for (int p = 0; p < 4; ++p) {
    int r = p * 8 + r0;
    tile[r][c] = src[(size_t)(k0 + r) * 1024 + n0 + c] * scale;
  }
  __syncthreads();
#pragma unroll
  for (int p = 0; p < 4; ++p) {
    int r = p * 8 + r0;
    dst[(size_t)(n0 + r) * 1024 + k0 + c] = f2b(tile[c][r]);
  }
}

__global__ void k_packbias(const float* __restrict__ bq, const float* __restrict__ bk,
                           const float* __restrict__ bv, float* __restrict__ out,
                           float qscale) {
  int t = blockIdx.x * 256 + threadIdx.x;
  float v = (t < 1024) ? bq[t] * qscale : (t < 2048 ? bk[t - 1024] : bv[t - 2048]);
  out[t] = v;
}

// ---------------- GEMM: C(Mx*) = A(MxK,bf16) * Bt(NxK,bf16)^T + bias ----------------
// 128x128 tile, BK=64, 4 waves (2x2 of 64x64), global_load_lds w=16, XOR chunk swizzle.
// n-blocks with n0 >= nsplit write bf16 V transposed into VT (B,H,HD,S) instead.
template <bool OUT_BF16>
__global__ __launch_bounds__(256, 2) void k_gemm_bt(
    const u16* __restrict__ A, const u16* __restrict__ Bt,
    const float* __restrict__ bias, void* __restrict__ Cout, u16* __restrict__ VT,
    int K, int ldC, int nsplit) {
  __shared__ u16 As[128 * 64];
  __shared__ u16 Bs[128 * 64];
  const int t = threadIdx.x;
  const int w = t >> 6, l = t & 63;
  const int lane15 = l & 15, quad = l >> 4;
  const int m0 = blockIdx.x * 128, n0 = blockIdx.y * 128;
  const int wm = (w >> 1) * 64, wn = (w & 1) * 64;

  const int srow = t >> 3, cp = t & 7;
  const u16* aSrc[4]; const u16* bSrc[4]; int ldsOff[4];
#pragma unroll
  for (int i = 0; i < 4; ++i) {
    int row = i * 32 + srow;           // 0..127 within tile
    int gc = cp ^ (row & 7);           // source chunk swizzle
    aSrc[i] = A + (size_t)(m0 + row) * K + gc * 8;
    bSrc[i] = Bt + (size_t)(n0 + row) * K + gc * 8;
    ldsOff[i] = (i * 32 + w * 8) * 64; // wave-uniform LDS base (elements)
  }

  f32x4 acc[4][4] = {};

  for (int kk = 0; kk < K; kk += 64) {
#pragma unroll
    for (int i = 0; i < 4; ++i) async16(aSrc[i] + kk, As + ldsOff[i]);
#pragma unroll
    for (int i = 0; i < 4; ++i) async16(bSrc[i] + kk, Bs + ldsOff[i]);
    __builtin_amdgcn_s_waitcnt(0);
    __syncthreads();

#pragma unroll
    for (int ks = 0; ks < 2; ++ks) {
      s16x8 af[4], bf[4];
#pragma unroll
      for (int mi = 0; mi < 4; ++mi) {
        int r = wm + mi * 16 + lane15;
        int c = ks * 4 + quad;
        af[mi] = *(const s16x8*)(As + r * 64 + (c ^ (r & 7)) * 8);
      }
#pragma unroll
      for (int ni = 0; ni < 4; ++ni) {
        int r = wn + ni * 16 + lane15;
        int c = ks * 4 + quad;
        bf[ni] = *(const s16x8*)(Bs + r * 64 + (c ^ (r & 7)) * 8);
      }
#pragma unroll
      for (int mi = 0; mi < 4; ++mi)
#pragma unroll
        for (int ni = 0; ni < 4; ++ni)
          acc[mi][ni] = __builtin_amdgcn_mfma_f32_16x16x32_bf16(af[mi], bf[ni], acc[mi][ni], 0, 0, 0);
    }
    __syncthreads();
  }

  const bool vpath = (VT != nullptr) && (n0 >= nsplit);
#pragma unroll
  for (int ni = 0; ni < 4; ++ni) {
    int gn = n0 + wn + ni * 16 + lane15;
    float bb = bias[gn];
    if (!vpath) {
#pragma unroll
      for (int mi = 0; mi < 4; ++mi) {
        int gmBase = m0 + wm + mi * 16 + quad * 4;
#pragma unroll
        for (int r = 0; r < 4; ++r) {
          float v = acc[mi][ni][r] + bb;
          if (OUT_BF16)
            ((u16*)Cout)[(size_t)(gmBase + r) * ldC + gn] = f2b(v);
          else
            ((float*)Cout)[(size_t)(gmBase + r) * ldC + gn] = v;
        }
      }
    } else {
      int gv = gn - nsplit;          // 0..1023
      int hh = gv >> 6, hd = gv & 63;
#pragma unroll
      for (int mi = 0; mi < 4; ++mi) {
        int gmBase = m0 + wm + mi * 16 + quad * 4;
        int bb2 = gmBase >> 11, s = gmBase & 2047;
        u32x2 o;
        o.x = pack2(acc[mi][ni][0] + bb, acc[mi][ni][1] + bb);
        o.y = pack2(acc[mi][ni][2] + bb, acc[mi][ni][3] + bb);
        *(u32x2*)(VT + (((size_t)(bb2 * 16 + hh) * 64 + hd) * 2048 + s)) = o;
      }
    }
  }
}

// ---------------- flash attention (transposed, no-max softmax, Bc=128, dbuf) ----------------
// block = 64 Q rows (4 waves x 16), 16 key tiles of 128, double-buffered staging:
// one barrier per iter, prefetch next tile into other buffer right after barrier.
// Per buf (16384 elems): K tile [0,8192) 128x64; V tile [8192,16384) as two
// 64x64 halves (keys 0-63 / 64-127), each R2's conflict-free layout.
__global__ __launch_bounds__(256, 2) void k_flash(
    const u16* __restrict__ qkv, const u16* __restrict__ vt, u16* __restrict__ ctx) {
  __shared__ u16 S[2][16384];
  const int t = threadIdx.x;
  const int w = t >> 6, l = t & 63;
  const int lane15 = l & 15, quad = l >> 4;
  const int qt = blockIdx.x, bh = blockIdx.y;
  const int b = bh >> 4, h = bh & 15;

  // Q fragment (B-operand layout): Q[qrow][dim]
  const int qrow = b * 2048 + qt * 64 + w * 16 + lane15;
  const u16* qp = qkv + (size_t)qrow * 2048 + h * 64 + quad * 8;
  s16x8 qf0 = *(const s16x8*)qp;
  s16x8 qf1 = *(const s16x8*)(qp + 32);

  // staging setup: 4 async16 for K (128 rows x 8 chunks), 4 for V (2 halves x 64 rows x 8 chunks)
  const int srow = t >> 3, cp = t & 7;
  const u16* kSrc[4]; const u16* vSrc[4]; int kOff[4]; int vOff[4];
#pragma unroll
  for (int i = 0; i < 4; ++i) {
    int krow = i * 32 + srow;                        // 0..127
    int xk = (krow & 3) | (((krow >> 3) & 1) << 2);  // K-tile swizzle
    kSrc[i] = qkv + (size_t)(b * 2048 + krow) * 2048 + 1024 + h * 64 + (cp ^ xk) * 8;
    kOff[i] = (i * 32 + w * 8) * 64;
    int vr = (i >> 1) * 32 + srow;                   // 0..63 (hd)
    vSrc[i] = vt + (size_t)bh * (64 * 2048) + (size_t)vr * 2048 + (i & 1) * 64 + (cp ^ (vr & 7)) * 8;
    vOff[i] = 8192 + (i & 1) * 4096 + (i >> 1) * 2048 + w * 512;
  }

  const int kr = (lane15 >> 2) * 8 + (lane15 & 3);  // permuted A-frag key row base
  f32x4 O[4] = {};
  f32x4 sacc = {};
  const u32x4 onesu = {0x3F803F80u, 0x3F803F80u, 0x3F803F80u, 0x3F803F80u};
  const s16x8 onesf = __builtin_bit_cast(s16x8, onesu);

  // prologue: stage tile 0 into buf 0
#pragma unroll
  for (int i = 0; i < 4; ++i) async16(kSrc[i], &S[0][kOff[i]]);
#pragma unroll
  for (int i = 0; i < 4; ++i) async16(vSrc[i], &S[0][vOff[i]]);

  for (int jt = 0; jt < 16; ++jt) {
    __builtin_amdgcn_s_waitcnt(0);   // staging for buf[jt&1] (issued last iter) has landed
    __syncthreads();
    const u16* Sb = S[jt & 1];
    if (jt < 15) {                   // prefetch next tile into the other buffer
      const size_t kAdv = (size_t)(jt + 1) * 128 * 2048;
      const int vAdv = (jt + 1) * 128;
      u16* D = S[(jt & 1) ^ 1];
#pragma unroll
      for (int i = 0; i < 4; ++i) async16(kSrc[i] + kAdv, D + kOff[i]);
#pragma unroll
      for (int i = 0; i < 4; ++i) async16(vSrc[i] + vAdv, D + vOff[i]);
    }

    // S^T = K Q^T : tile tt row (quad*4+r) -> key quad*8+r +4*(tt&1)+32*(tt>>1)
    f32x4 st[8] = {};
#pragma unroll
    for (int ks2 = 0; ks2 < 2; ++ks2) {
      s16x8 qf = ks2 ? qf1 : qf0;
#pragma unroll
      for (int tt = 0; tt < 8; ++tt) {
        int rr = kr + (tt & 1) * 4 + (tt >> 1) * 32;
        int xk = (rr & 3) | (((rr >> 3) & 1) << 2);
        s16x8 kf = *(const s16x8*)(Sb + rr * 64 + ((ks2 * 4 + quad) ^ xk) * 8);
        st[tt] = __builtin_amdgcn_mfma_f32_16x16x32_bf16(kf, qf, st[tt], 0, 0, 0);
      }
    }

    // per 32-key step: exp2 -> pack -> l-sum MFMA + PV MFMAs
#pragma unroll
    for (int ks = 0; ks < 4; ++ks) {
      float p0 = EXP2(st[2 * ks][0]), p1 = EXP2(st[2 * ks][1]);
      float p2 = EXP2(st[2 * ks][2]), p3 = EXP2(st[2 * ks][3]);
      float p4 = EXP2(st[2 * ks + 1][0]), p5 = EXP2(st[2 * ks + 1][1]);
      float p6 = EXP2(st[2 * ks + 1][2]), p7 = EXP2(st[2 * ks + 1][3]);
      u32x4 pu = {pack2(p0, p1), pack2(p2, p3), pack2(p4, p5), pack2(p6, p7)};
      s16x8 pf = __builtin_bit_cast(s16x8, pu);
      sacc = __builtin_amdgcn_mfma_f32_16x16x32_bf16(onesf, pf, sacc, 0, 0, 0);
      const u16* Vh = Sb + 8192 + (ks >> 1) * 4096;   // key half
      int c7 = (ks & 1) * 4 + quad;
#pragma unroll
      for (int co = 0; co < 4; ++co) {
        int rr = co * 16 + lane15;
        s16x8 vf = *(const s16x8*)(Vh + rr * 64 + ((c7 ^ (rr & 7))) * 8);
        O[co] = __builtin_amdgcn_mfma_f32_16x16x32_bf16(vf, pf, O[co], 0, 0, 0);
      }
    }
  }

  // l fully summed per q via ones-MFMA: no cross-lane reduction
  float inv = 1.0f / sacc[0];
#pragma unroll
  for (int co = 0; co < 4; ++co) {
    u32x2 o;
    o.x = pack2(O[co][0] * inv, O[co][1] * inv);
    o.y = pack2(O[co][2] * inv, O[co][3] * inv);
    *(u32x2*)(ctx + (size_t)qrow * 1024 + h * 64 + co * 16 + quad * 4) = o;
  }
}

// ---------------- workspace layout (bytes) ----------------
static constexpr size_t OFF_XB  = 0;                        // 16 MB  x bf16 (8192x1024)
static constexpr size_t OFF_WT  = OFF_XB + (16u << 20);     // 6 MB   Wqkv^T bf16 (3072x1024)
static constexpr size_t OFF_WOT = OFF_WT + (6u << 20);      // 2 MB   Wo^T bf16 (1024x1024)
static constexpr size_t OFF_B3  = OFF_WOT + (2u << 20);     // 64 KB  bias3072 fp32
static constexpr size_t OFF_QKV = OFF_B3 + (1u << 20);      // 32 MB  q|k bf16 (8192x2048)
static constexpr size_t OFF_VT  = OFF_QKV + (32u << 20);    // 16 MB  v^T bf16 (B,H,64,2048)
static constexpr size_t OFF_CTX = OFF_VT + (16u << 20);     // 16 MB  ctx bf16 (8192x1024)

extern "C" void kernel_launch(void* const* d_in, const int* in_sizes, int n_in,
                              void* d_out, int out_size, void* d_ws, size_t ws_size,
                              hipStream_t stream) {
  const float* x  = (const float*)d_in[0];
  const float* Wq = (const float*)d_in[1];
  const float* bq = (const float*)d_in[2];
  const float* Wk = (const float*)d_in[3];
  const float* bk = (const float*)d_in[4];
  const float* Wv = (const float*)d_in[5];
  const float* bv = (const float*)d_in[6];
  const float* Wo = (const float*)d_in[7];
  const float* bo = (const float*)d_in[8];
  char* ws = (char*)d_ws;
  u16* xb    = (u16*)(ws + OFF_XB);
  u16* wt    = (u16*)(ws + OFF_WT);
  u16* wot   = (u16*)(ws + OFF_WOT);
  float* b3  = (float*)(ws + OFF_B3);
  u16* qkv   = (u16*)(ws + OFF_QKV);
  u16* vtb   = (u16*)(ws + OFF_VT);
  u16* ctx   = (u16*)(ws + OFF_CTX);
  float* out = (float*)d_out;

  const float QSCALE = 0.125f * 1.44269504f;  // 1/sqrt(64) * log2(e): exp2-domain scores

  k_cast<<<8192, 256, 0, stream>>>(x, xb);
  k_packw_all<<<dim3(32, 32, 4), 256, 0, stream>>>(Wq, Wk, Wv, Wo, wt, wot, QSCALE);
  k_packbias<<<12, 256, 0, stream>>>(bq, bk, bv, b3, QSCALE);
  // QKV GEMM: Q,K -> qkv (ldC=2048); V (n>=2048) -> vtb transposed
  k_gemm_bt<true><<<dim3(64, 24), 256, 0, stream>>>(xb, wt, b3, qkv, vtb, 1024, 2048, 2048);
  k_flash<<<dim3(32, 64), 256, 0, stream>>>(qkv, vtb, ctx);
  // out projection -> fp32 d_out
  k_gemm_bt<false><<<dim3(64, 8), 256, 0, stream>>>(ctx, wot, bo, out, nullptr, 1024, 1024, 1 << 30);
}

// Round 5
// 287.087 us; speedup vs baseline: 1.0302x; 1.0302x over previous
//
#include <hip/hip_runtime.h>

// MHA fwd: B=4 S=2048 D=1024 H=16 HD=64. fp32 in/out, bf16 MFMA compute.
// R5: flash = Bc=128 single-buffer (R3 occupancy) + split-half conflict-free Vs
// (R4 layout, 0 conflicts) + XCD-friendly grid (bh fastest: each XCD's L2 holds
// its 8 heads' K/V = 4 MB). GEMM unchanged (R2/R4 structure).

typedef unsigned short u16;
typedef __attribute__((ext_vector_type(4))) float f32x4;
typedef __attribute__((ext_vector_type(8))) short s16x8;
typedef __attribute__((ext_vector_type(4))) unsigned short u16x4;
typedef __attribute__((ext_vector_type(2))) unsigned int u32x2;
typedef __attribute__((ext_vector_type(4))) unsigned int u32x4;

#define DEV __device__ __forceinline__

#if __has_builtin(__builtin_amdgcn_exp2f)
#define EXP2(x) __builtin_amdgcn_exp2f(x)
#else
#define EXP2(x) exp2f(x)
#endif

DEV u16 f2b(float f) {  // fp32 -> bf16 RNE
  unsigned u = __float_as_uint(f);
  u += 0x7fffu + ((u >> 16) & 1u);
  return (u16)(u >> 16);
}

DEV unsigned pack2(float a, float b) {  // two fp32 -> packed bf16x2
#if __has_builtin(__builtin_amdgcn_cvt_pk_bf16_f32)
  typedef __attribute__((ext_vector_type(2))) __bf16 bf16x2;
  bf16x2 r = __builtin_amdgcn_cvt_pk_bf16_f32(a, b);
  return __builtin_bit_cast(unsigned, r);
#else
  return (unsigned)f2b(a) | ((unsigned)f2b(b) << 16);
#endif
}

DEV void async16(const void* g, void* l) {  // 16B global -> LDS direct
  __builtin_amdgcn_global_load_lds(
      (const __attribute__((address_space(1))) unsigned int*)g,
      (__attribute__((address_space(3))) unsigned int*)l, 16, 0, 0);
}

// ---------------- cast x -> bf16 ----------------
__global__ void k_cast(const float* __restrict__ x, u16* __restrict__ xb) {
  int i = (blockIdx.x * 256 + threadIdx.x) * 4;
  float4 v = *(const float4*)(x + i);
  u16x4 o;
  o.x = f2b(v.x); o.y = f2b(v.y); o.z = f2b(v.z); o.w = f2b(v.w);
  *(u16x4*)(xb + i) = o;
}

// ---------------- transpose+convert all 4 weights (1024x1024) -> Bt bf16 ----------------
__global__ void k_packw_all(const float* __restrict__ Wq, const float* __restrict__ Wk,
                            const float* __restrict__ Wv, const float* __restrict__ Wo,
                            u16* __restrict__ wt, u16* __restrict__ wot, float qscale) {
  const float* src; u16* dst; float scale = 1.0f;
  switch (blockIdx.z) {
    case 0: src = Wq; dst = wt; scale = qscale; break;
    case 1: src = Wk; dst = wt + 1024 * 1024; break;
    case 2: src = Wv; dst = wt + 2 * 1024 * 1024; break;
    default: src = Wo; dst = wot; break;
  }
  __shared__ float tile[32][33];
  int t = threadIdx.x;
  int k0 = blockIdx.x * 32, n0 = blockIdx.y * 32;
  int c = t & 31, r0 = t >> 5;
#pragma unroll
  for (int p = 0; p < 4; ++p) {
    int r = p * 8 + r0;
    tile[r][c] = src[(size_t)(k0 + r) * 1024 + n0 + c] * scale;
  }
  __syncthreads();
#pragma unroll
  for (int p = 0; p < 4; ++p) {
    int r = p * 8 + r0;
    dst[(size_t)(n0 + r) * 1024 + k0 + c] = f2b(tile[c][r]);
  }
}

__global__ void k_packbias(const float* __restrict__ bq, const float* __restrict__ bk,
                           const float* __restrict__ bv, float* __restrict__ out,
                           float qscale) {
  int t = blockIdx.x * 256 + threadIdx.x;
  float v = (t < 1024) ? bq[t] * qscale : (t < 2048 ? bk[t - 1024] : bv[t - 2048]);
  out[t] = v;
}

// ---------------- GEMM: C(Mx*) = A(MxK,bf16) * Bt(NxK,bf16)^T + bias ----------------
// 128x128 tile, BK=64, 4 waves (2x2 of 64x64), global_load_lds w=16, XOR chunk swizzle.
// n-blocks with n0 >= nsplit write bf16 V transposed into VT (B,H,HD,S) instead.
template <bool OUT_BF16>
__global__ __launch_bounds__(256, 2) void k_gemm_bt(
    const u16* __restrict__ A, const u16* __restrict__ Bt,
    const float* __restrict__ bias, void* __restrict__ Cout, u16* __restrict__ VT,
    int K, int ldC, int nsplit) {
  __shared__ u16 As[128 * 64];
  __shared__ u16 Bs[128 * 64];
  const int t = threadIdx.x;
  const int w = t >> 6, l = t & 63;
  const int lane15 = l & 15, quad = l >> 4;
  const int m0 = blockIdx.x * 128, n0 = blockIdx.y * 128;
  const int wm = (w >> 1) * 64, wn = (w & 1) * 64;

  const int srow = t >> 3, cp = t & 7;
  const u16* aSrc[4]; const u16* bSrc[4]; int ldsOff[4];
#pragma unroll
  for (int i = 0; i < 4; ++i) {
    int row = i * 32 + srow;           // 0..127 within tile
    int gc = cp ^ (row & 7);           // source chunk swizzle
    aSrc[i] = A + (size_t)(m0 + row) * K + gc * 8;
    bSrc[i] = Bt + (size_t)(n0 + row) * K + gc * 8;
    ldsOff[i] = (i * 32 + w * 8) * 64; // wave-uniform LDS base (elements)
  }

  f32x4 acc[4][4] = {};

  for (int kk = 0; kk < K; kk += 64) {
#pragma unroll
    for (int i = 0; i < 4; ++i) async16(aSrc[i] + kk, As + ldsOff[i]);
#pragma unroll
    for (int i = 0; i < 4; ++i) async16(bSrc[i] + kk, Bs + ldsOff[i]);
    __builtin_amdgcn_s_waitcnt(0);
    __syncthreads();

#pragma unroll
    for (int ks = 0; ks < 2; ++ks) {
      s16x8 af[4], bf[4];
#pragma unroll
      for (int mi = 0; mi < 4; ++mi) {
        int r = wm + mi * 16 + lane15;
        int c = ks * 4 + quad;
        af[mi] = *(const s16x8*)(As + r * 64 + (c ^ (r & 7)) * 8);
      }
#pragma unroll
      for (int ni = 0; ni < 4; ++ni) {
        int r = wn + ni * 16 + lane15;
        int c = ks * 4 + quad;
        bf[ni] = *(const s16x8*)(Bs + r * 64 + (c ^ (r & 7)) * 8);
      }
#pragma unroll
      for (int mi = 0; mi < 4; ++mi)
#pragma unroll
        for (int ni = 0; ni < 4; ++ni)
          acc[mi][ni] = __builtin_amdgcn_mfma_f32_16x16x32_bf16(af[mi], bf[ni], acc[mi][ni], 0, 0, 0);
    }
    __syncthreads();
  }

  const bool vpath = (VT != nullptr) && (n0 >= nsplit);
#pragma unroll
  for (int ni = 0; ni < 4; ++ni) {
    int gn = n0 + wn + ni * 16 + lane15;
    float bb = bias[gn];
    if (!vpath) {
#pragma unroll
      for (int mi = 0; mi < 4; ++mi) {
        int gmBase = m0 + wm + mi * 16 + quad * 4;
#pragma unroll
        for (int r = 0; r < 4; ++r) {
          float v = acc[mi][ni][r] + bb;
          if (OUT_BF16)
            ((u16*)Cout)[(size_t)(gmBase + r) * ldC + gn] = f2b(v);
          else
            ((float*)Cout)[(size_t)(gmBase + r) * ldC + gn] = v;
        }
      }
    } else {
      int gv = gn - nsplit;          // 0..1023
      int hh = gv >> 6, hd = gv & 63;
#pragma unroll
      for (int mi = 0; mi < 4; ++mi) {
        int gmBase = m0 + wm + mi * 16 + quad * 4;
        int bb2 = gmBase >> 11, s = gmBase & 2047;
        u32x2 o;
        o.x = pack2(acc[mi][ni][0] + bb, acc[mi][ni][1] + bb);
        o.y = pack2(acc[mi][ni][2] + bb, acc[mi][ni][3] + bb);
        *(u32x2*)(VT + (((size_t)(bb2 * 16 + hh) * 64 + hd) * 2048 + s)) = o;
      }
    }
  }
}

// ---------------- flash attention (transposed, no-max softmax, Bc=128) ----------------
// block = 64 Q rows (4 waves x 16), 16 key tiles of 128, single-buffered.
// LDS: K tile [0,8192) 128x64 (xor-swizzled); V tile [8192,16384) as two 64x64
// halves (keys 0-63 / 64-127), each conflict-free (validated R4: 0 conflicts).
// grid.x = bh (fastest) so each XCD's L2 caches only bh%8==xcd K/V (4 MB).
__global__ __launch_bounds__(256, 4) void k_flash(
    const u16* __restrict__ qkv, const u16* __restrict__ vt, u16* __restrict__ ctx) {
  __shared__ u16 S[16384];
  const int t = threadIdx.x;
  const int w = t >> 6, l = t & 63;
  const int lane15 = l & 15, quad = l >> 4;
  const int bh = blockIdx.x, qt = blockIdx.y;
  const int b = bh >> 4, h = bh & 15;

  // Q fragment (B-operand layout): Q[qrow][dim]
  const int qrow = b * 2048 + qt * 64 + w * 16 + lane15;
  const u16* qp = qkv + (size_t)qrow * 2048 + h * 64 + quad * 8;
  s16x8 qf0 = *(const s16x8*)qp;
  s16x8 qf1 = *(const s16x8*)(qp + 32);

  // staging: 4 async16 for K (128 rows x 8 chunks), 4 for V (2 halves x 64 rows x 8 chunks)
  const int srow = t >> 3, cp = t & 7;
  const u16* kSrc[4]; const u16* vSrc[4]; int kOff[4]; int vOff[4];
#pragma unroll
  for (int i = 0; i < 4; ++i) {
    int krow = i * 32 + srow;                        // 0..127
    int xk = (krow & 3) | (((krow >> 3) & 1) << 2);  // K-tile swizzle
    kSrc[i] = qkv + (size_t)(b * 2048 + krow) * 2048 + 1024 + h * 64 + (cp ^ xk) * 8;
    kOff[i] = (i * 32 + w * 8) * 64;
    int vr = (i >> 1) * 32 + srow;                   // 0..63 (hd)
    vSrc[i] = vt + (size_t)bh * (64 * 2048) + (size_t)vr * 2048 + (i & 1) * 64 + (cp ^ (vr & 7)) * 8;
    vOff[i] = 8192 + (i & 1) * 4096 + (i >> 1) * 2048 + w * 512;
  }

  const int kr = (lane15 >> 2) * 8 + (lane15 & 3);  // permuted A-frag key row base
  f32x4 O[4] = {};
  f32x4 sacc = {};
  const u32x4 onesu = {0x3F803F80u, 0x3F803F80u, 0x3F803F80u, 0x3F803F80u};
  const s16x8 onesf = __builtin_bit_cast(s16x8, onesu);

  for (int jt = 0; jt < 16; ++jt) {
    const size_t kAdv = (size_t)jt * 128 * 2048;
    const int vAdv = jt * 128;
#pragma unroll
    for (int i = 0; i < 4; ++i) async16(kSrc[i] + kAdv, S + kOff[i]);
#pragma unroll
    for (int i = 0; i < 4; ++i) async16(vSrc[i] + vAdv, S + vOff[i]);
    __builtin_amdgcn_s_waitcnt(0);
    __syncthreads();

    // S^T = K Q^T : tile tt row (quad*4+r) -> key quad*8+r +4*(tt&1)+32*(tt>>1)
    f32x4 st[8] = {};
#pragma unroll
    for (int ks2 = 0; ks2 < 2; ++ks2) {
      s16x8 qf = ks2 ? qf1 : qf0;
#pragma unroll
      for (int tt = 0; tt < 8; ++tt) {
        int rr = kr + (tt & 1) * 4 + (tt >> 1) * 32;
        int xk = (rr & 3) | (((rr >> 3) & 1) << 2);
        s16x8 kf = *(const s16x8*)(S + rr * 64 + ((ks2 * 4 + quad) ^ xk) * 8);
        st[tt] = __builtin_amdgcn_mfma_f32_16x16x32_bf16(kf, qf, st[tt], 0, 0, 0);
      }
    }

    // per 32-key step: exp2 -> pack -> l-sum MFMA + PV MFMAs
#pragma unroll
    for (int ks = 0; ks < 4; ++ks) {
      float p0 = EXP2(st[2 * ks][0]), p1 = EXP2(st[2 * ks][1]);
      float p2 = EXP2(st[2 * ks][2]), p3 = EXP2(st[2 * ks][3]);
      float p4 = EXP2(st[2 * ks + 1][0]), p5 = EXP2(st[2 * ks + 1][1]);
      float p6 = EXP2(st[2 * ks + 1][2]), p7 = EXP2(st[2 * ks + 1][3]);
      u32x4 pu = {pack2(p0, p1), pack2(p2, p3), pack2(p4, p5), pack2(p6, p7)};
      s16x8 pf = __builtin_bit_cast(s16x8, pu);
      sacc = __builtin_amdgcn_mfma_f32_16x16x32_bf16(onesf, pf, sacc, 0, 0, 0);
      const u16* Vh = S + 8192 + (ks >> 1) * 4096;   // key half
      int c7 = (ks & 1) * 4 + quad;
#pragma unroll
      for (int co = 0; co < 4; ++co) {
        int rr = co * 16 + lane15;
        s16x8 vf = *(const s16x8*)(Vh + rr * 64 + ((c7 ^ (rr & 7))) * 8);
        O[co] = __builtin_amdgcn_mfma_f32_16x16x32_bf16(vf, pf, O[co], 0, 0, 0);
      }
    }
    __syncthreads();
  }

  // l fully summed per q via ones-MFMA: no cross-lane reduction
  float inv = 1.0f / sacc[0];
#pragma unroll
  for (int co = 0; co < 4; ++co) {
    u32x2 o;
    o.x = pack2(O[co][0] * inv, O[co][1] * inv);
    o.y = pack2(O[co][2] * inv, O[co][3] * inv);
    *(u32x2*)(ctx + (size_t)qrow * 1024 + h * 64 + co * 16 + quad * 4) = o;
  }
}

// ---------------- workspace layout (bytes) ----------------
static constexpr size_t OFF_XB  = 0;                        // 16 MB  x bf16 (8192x1024)
static constexpr size_t OFF_WT  = OFF_XB + (16u << 20);     // 6 MB   Wqkv^T bf16 (3072x1024)
static constexpr size_t OFF_WOT = OFF_WT + (6u << 20);      // 2 MB   Wo^T bf16 (1024x1024)
static constexpr size_t OFF_B3  = OFF_WOT + (2u << 20);     // 64 KB  bias3072 fp32
static constexpr size_t OFF_QKV = OFF_B3 + (1u << 20);      // 32 MB  q|k bf16 (8192x2048)
static constexpr size_t OFF_VT  = OFF_QKV + (32u << 20);    // 16 MB  v^T bf16 (B,H,64,2048)
static constexpr size_t OFF_CTX = OFF_VT + (16u << 20);     // 16 MB  ctx bf16 (8192x1024)

extern "C" void kernel_launch(void* const* d_in, const int* in_sizes, int n_in,
                              void* d_out, int out_size, void* d_ws, size_t ws_size,
                              hipStream_t stream) {
  const float* x  = (const float*)d_in[0];
  const float* Wq = (const float*)d_in[1];
  const float* bq = (const float*)d_in[2];
  const float* Wk = (const float*)d_in[3];
  const float* bk = (const float*)d_in[4];
  const float* Wv = (const float*)d_in[5];
  const float* bv = (const float*)d_in[6];
  const float* Wo = (const float*)d_in[7];
  const float* bo = (const float*)d_in[8];
  char* ws = (char*)d_ws;
  u16* xb    = (u16*)(ws + OFF_XB);
  u16* wt    = (u16*)(ws + OFF_WT);
  u16* wot   = (u16*)(ws + OFF_WOT);
  float* b3  = (float*)(ws + OFF_B3);
  u16* qkv   = (u16*)(ws + OFF_QKV);
  u16* vtb   = (u16*)(ws + OFF_VT);
  u16* ctx   = (u16*)(ws + OFF_CTX);
  float* out = (float*)d_out;

  const float QSCALE = 0.125f * 1.44269504f;  // 1/sqrt(64) * log2(e): exp2-domain scores

  k_cast<<<8192, 256, 0, stream>>>(x, xb);
  k_packw_all<<<dim3(32, 32, 4), 256, 0, stream>>>(Wq, Wk, Wv, Wo, wt, wot, QSCALE);
  k_packbias<<<12, 256, 0, stream>>>(bq, bk, bv, b3, QSCALE);
  // QKV GEMM: Q,K -> qkv (ldC=2048); V (n>=2048) -> vtb transposed
  k_gemm_bt<true><<<dim3(64, 24), 256, 0, stream>>>(xb, wt, b3, qkv, vtb, 1024, 2048, 2048);
  // flash: grid.x = bh (64), grid.y = qt (32)
  k_flash<<<dim3(64, 32), 256, 0, stream>>>(qkv, vtb, ctx);
  // out projection -> fp32 d_out
  k_gemm_bt<false><<<dim3(64, 8), 256, 0, stream>>>(ctx, wot, bo, out, nullptr, 1024, 1024, 1 << 30);
}

// Round 6
// 275.846 us; speedup vs baseline: 1.0722x; 1.0408x over previous
//
#include <hip/hip_runtime.h>

// MHA fwd: B=4 S=2048 D=1024 H=16 HD=64. fp32 in/out, bf16 MFMA compute.
// R6: flash Bc=64 DOUBLE-buffered (2x16KB = 32KB, occupancy preserved; one
// barrier/iter, prefetch a full compute-phase ahead -> vmcnt drain off the
// critical path). GEMM bf16 epilogues via XOR-swizzled LDS transpose ->
// coalesced dwordx4 stores (Q|K swapped-operand, V-transpose path unswapped).

typedef unsigned short u16;
typedef __attribute__((ext_vector_type(4))) float f32x4;
typedef __attribute__((ext_vector_type(8))) short s16x8;
typedef __attribute__((ext_vector_type(4))) unsigned short u16x4;
typedef __attribute__((ext_vector_type(2))) unsigned int u32x2;
typedef __attribute__((ext_vector_type(4))) unsigned int u32x4;

#define DEV __device__ __forceinline__

#if __has_builtin(__builtin_amdgcn_exp2f)
#define EXP2(x) __builtin_amdgcn_exp2f(x)
#else
#define EXP2(x) exp2f(x)
#endif

DEV u16 f2b(float f) {  // fp32 -> bf16 RNE
  unsigned u = __float_as_uint(f);
  u += 0x7fffu + ((u >> 16) & 1u);
  return (u16)(u >> 16);
}

DEV unsigned pack2(float a, float b) {  // two fp32 -> packed bf16x2
#if __has_builtin(__builtin_amdgcn_cvt_pk_bf16_f32)
  typedef __attribute__((ext_vector_type(2))) __bf16 bf16x2;
  bf16x2 r = __builtin_amdgcn_cvt_pk_bf16_f32(a, b);
  return __builtin_bit_cast(unsigned, r);
#else
  return (unsigned)f2b(a) | ((unsigned)f2b(b) << 16);
#endif
}

DEV void async16(const void* g, void* l) {  // 16B global -> LDS direct
  __builtin_amdgcn_global_load_lds(
      (const __attribute__((address_space(1))) unsigned int*)g,
      (__attribute__((address_space(3))) unsigned int*)l, 16, 0, 0);
}

// ---------------- cast x -> bf16 ----------------
__global__ void k_cast(const float* __restrict__ x, u16* __restrict__ xb) {
  int i = (blockIdx.x * 256 + threadIdx.x) * 4;
  float4 v = *(const float4*)(x + i);
  u16x4 o;
  o.x = f2b(v.x); o.y = f2b(v.y); o.z = f2b(v.z); o.w = f2b(v.w);
  *(u16x4*)(xb + i) = o;
}

// ---------------- transpose+convert all 4 weights (1024x1024) -> Bt bf16 ----------------
__global__ void k_packw_all(const float* __restrict__ Wq, const float* __restrict__ Wk,
                            const float* __restrict__ Wv, const float* __restrict__ Wo,
                            u16* __restrict__ wt, u16* __restrict__ wot, float qscale) {
  const float* src; u16* dst; float scale = 1.0f;
  switch (blockIdx.z) {
    case 0: src = Wq; dst = wt; scale = qscale; break;
    case 1: src = Wk; dst = wt + 1024 * 1024; break;
    case 2: src = Wv; dst = wt + 2 * 1024 * 1024; break;
    default: src = Wo; dst = wot; break;
  }
  __shared__ float tile[32][33];
  int t = threadIdx.x;
  int k0 = blockIdx.x * 32, n0 = blockIdx.y * 32;
  int c = t & 31, r0 = t >> 5;
#pragma unroll
  for (int p = 0; p < 4; ++p) {
    int r = p * 8 + r0;
    tile[r][c] = src[(size_t)(k0 + r) * 1024 + n0 + c] * scale;
  }
  __syncthreads();
#pragma unroll
  for (int p = 0; p < 4; ++p) {
    int r = p * 8 + r0;
    dst[(size_t)(n0 + r) * 1024 + k0 + c] = f2b(tile[c][r]);
  }
}

__global__ void k_packbias(const float* __restrict__ bq, const float* __restrict__ bk,
                           const float* __restrict__ bv, float* __restrict__ out,
                           float qscale) {
  int t = blockIdx.x * 256 + threadIdx.x;
  float v = (t < 1024) ? bq[t] * qscale : (t < 2048 ? bk[t - 1024] : bv[t - 2048]);
  out[t] = v;
}

// ---------------- GEMM: C = A(MxK,bf16) * Bt(NxK,bf16)^T + bias ----------------
// 128x128 tile, BK=64, 4 waves (2x2 of 64x64), global_load_lds w=16, XOR chunk swizzle.
// MODE 0: Q|K path. swapped MFMA -> LDS transpose (16B-block XOR swizzle) ->
//         coalesced dwordx4 bf16 row-major stores.
// MODE 1: out path. unswapped, direct fp32 stores (64B segments).
// MODE 2: V path. unswapped -> LDS transpose -> coalesced stores into VT (B,H,HD,S).
template <int MODE>
__global__ __launch_bounds__(256, 2) void k_gemm_bt(
    const u16* __restrict__ A, const u16* __restrict__ Bt,
    const float* __restrict__ bias, void* __restrict__ Cout, u16* __restrict__ VT,
    int K, int ldC, int nbase) {
  __shared__ u16 SH[16384];           // As [0,8192) | Bs [8192,16384); reused by epilogue
  u16* As = SH;
  u16* Bs = SH + 8192;
  const int t = threadIdx.x;
  const int w = t >> 6, l = t & 63;
  const int lane15 = l & 15, quad = l >> 4;
  const int m0 = blockIdx.x * 128, n0 = nbase + blockIdx.y * 128;
  const int wm = (w >> 1) * 64, wn = (w & 1) * 64;

  const int srow = t >> 3, cp = t & 7;
  const u16* aSrc[4]; const u16* bSrc[4]; int ldsOff[4];
#pragma unroll
  for (int i = 0; i < 4; ++i) {
    int row = i * 32 + srow;           // 0..127 within tile
    int gc = cp ^ (row & 7);           // source chunk swizzle
    aSrc[i] = A + (size_t)(m0 + row) * K + gc * 8;
    bSrc[i] = Bt + (size_t)(n0 + row) * K + gc * 8;
    ldsOff[i] = (i * 32 + w * 8) * 64; // wave-uniform LDS base (elements)
  }

  f32x4 acc[4][4] = {};

  for (int kk = 0; kk < K; kk += 64) {
#pragma unroll
    for (int i = 0; i < 4; ++i) async16(aSrc[i] + kk, As + ldsOff[i]);
#pragma unroll
    for (int i = 0; i < 4; ++i) async16(bSrc[i] + kk, Bs + ldsOff[i]);
    __builtin_amdgcn_s_waitcnt(0);
    __syncthreads();

#pragma unroll
    for (int ks = 0; ks < 2; ++ks) {
      s16x8 af[4], bf[4];
#pragma unroll
      for (int mi = 0; mi < 4; ++mi) {
        int r = wm + mi * 16 + lane15;
        int c = ks * 4 + quad;
        af[mi] = *(const s16x8*)(As + r * 64 + (c ^ (r & 7)) * 8);
      }
#pragma unroll
      for (int ni = 0; ni < 4; ++ni) {
        int r = wn + ni * 16 + lane15;
        int c = ks * 4 + quad;
        bf[ni] = *(const s16x8*)(Bs + r * 64 + (c ^ (r & 7)) * 8);
      }
#pragma unroll
      for (int mi = 0; mi < 4; ++mi)
#pragma unroll
        for (int ni = 0; ni < 4; ++ni)
          acc[mi][ni] = (MODE == 0)
              ? __builtin_amdgcn_mfma_f32_16x16x32_bf16(bf[ni], af[mi], acc[mi][ni], 0, 0, 0)
              : __builtin_amdgcn_mfma_f32_16x16x32_bf16(af[mi], bf[ni], acc[mi][ni], 0, 0, 0);
    }
    __syncthreads();                  // also protects SH reuse by the epilogue
  }

  if (MODE == 0) {
    // swapped layout (R3-validated): row gm = m0+wm+mi*16+lane15,
    // cols gnb..gnb+3 = n0+wn+ni*16+quad*4 (+r). Stage wave's 64x64 bf16 in LDS.
    u16* W = SH + w * 4096;
#pragma unroll
    for (int ni = 0; ni < 4; ++ni) {
      int gnb = n0 + wn + ni * 16 + quad * 4;
      float4 bb = *(const float4*)(bias + gnb);
#pragma unroll
      for (int mi = 0; mi < 4; ++mi) {
        int mloc = mi * 16 + lane15;
        int nloc = ni * 16 + quad * 4;
        int blk = (nloc >> 3) ^ (mloc & 7);   // 16B-block XOR swizzle
        u32x2 o;
        o.x = pack2(acc[mi][ni][0] + bb.x, acc[mi][ni][1] + bb.y);
        o.y = pack2(acc[mi][ni][2] + bb.z, acc[mi][ni][3] + bb.w);
        *(u32x2*)(W + mloc * 64 + blk * 8 + (quad & 1) * 4) = o;
      }
    }
    const int l8 = l & 7, lr = l >> 3;        // wave-private region: no barrier
#pragma unroll
    for (int it = 0; it < 8; ++it) {
      int mloc = it * 8 + lr;
      int lb = l8 ^ (mloc & 7);               // logical 8-col block
      s16x8 v = *(const s16x8*)(W + mloc * 64 + l8 * 8);
      int gm = m0 + wm + mloc;
      *(s16x8*)((u16*)Cout + (size_t)gm * ldC + n0 + wn + lb * 8) = v;
    }
  } else if (MODE == 1) {
    // fp32 direct (64B segments per quad-row)
#pragma unroll
    for (int ni = 0; ni < 4; ++ni) {
      int gn = n0 + wn + ni * 16 + lane15;
      float bb = bias[gn];
#pragma unroll
      for (int mi = 0; mi < 4; ++mi) {
        int gmBase = m0 + wm + mi * 16 + quad * 4;
#pragma unroll
        for (int r = 0; r < 4; ++r)
          ((float*)Cout)[(size_t)(gmBase + r) * ldC + gn] = acc[mi][ni][r] + bb;
      }
    }
  } else {
    // V path, unswapped: col gn -> hd (lane15), rows -> s (quad*4+r). Stage
    // [hd][s] 64x64 in LDS, then 128B-contiguous stores into VT rows.
    u16* W = SH + w * 4096;
#pragma unroll
    for (int ni = 0; ni < 4; ++ni) {
      int gn = n0 + wn + ni * 16 + lane15;
      float bb = bias[gn];
#pragma unroll
      for (int mi = 0; mi < 4; ++mi) {
        int nloc = ni * 16 + lane15;
        int mloc = mi * 16 + quad * 4;
        int blk = (mloc >> 3) ^ (nloc & 7);
        u32x2 o;
        o.x = pack2(acc[mi][ni][0] + bb, acc[mi][ni][1] + bb);
        o.y = pack2(acc[mi][ni][2] + bb, acc[mi][ni][3] + bb);
        *(u32x2*)(W + nloc * 64 + blk * 8 + (quad & 1) * 4) = o;
      }
    }
    const int l8 = l & 7, lr = l >> 3;
#pragma unroll
    for (int it = 0; it < 8; ++it) {
      int nloc = it * 8 + lr;
      int lb = l8 ^ (nloc & 7);
      s16x8 v = *(const s16x8*)(W + nloc * 64 + l8 * 8);
      int gv = (n0 - 2048) + wn + nloc;       // 0..1023
      int hh = gv >> 6, hd = gv & 63;
      int gm = m0 + wm + lb * 8;              // 8 contiguous s
      int bb2 = gm >> 11, s = gm & 2047;
      *(s16x8*)(VT + (((size_t)(bb2 * 16 + hh) * 64 + hd) * 2048 + s)) = v;
    }
  }
}

// ---------------- flash attention (transposed, no-max softmax, Bc=64, dbuf) ----------------
// block = 64 Q rows (4 waves x 16), 32 key tiles of 64, double-buffered 2x16KB:
// one barrier/iter; prefetch jt+1 right after the barrier so the next iter's
// vmcnt drain waits on loads issued a full compute phase earlier.
// Per buf (8192 elems): K tile [0,4096) 64x64 (permuted-row xor swizzle, R2-validated);
// V tile [4096,8192) 64x64 (R2-validated). grid.x = bh -> per-XCD K/V locality.
__global__ __launch_bounds__(256, 5) void k_flash(
    const u16* __restrict__ qkv, const u16* __restrict__ vt, u16* __restrict__ ctx) {
  __shared__ u16 S[2][8192];
  const int t = threadIdx.x;
  const int w = t >> 6, l = t & 63;
  const int lane15 = l & 15, quad = l >> 4;
  const int bh = blockIdx.x, qt = blockIdx.y;
  const int b = bh >> 4, h = bh & 15;

  // Q fragment (B-operand layout): Q[qrow][dim]
  const int qrow = b * 2048 + qt * 64 + w * 16 + lane15;
  const u16* qp = qkv + (size_t)qrow * 2048 + h * 64 + quad * 8;
  s16x8 qf0 = *(const s16x8*)(qp);
  s16x8 qf1 = *(const s16x8*)(qp + 32);

  // staging: 2 async16 for K (64 rows x 8 chunks), 2 for V (64 rows x 8 chunks)
  const int srow = t >> 3, cp = t & 7;
  const u16* kSrc[2]; const u16* vSrc[2]; int kOff[2]; int vOff[2];
#pragma unroll
  for (int i = 0; i < 2; ++i) {
    int row = i * 32 + srow;                         // 0..63
    int xk = (row & 3) | (((row >> 3) & 1) << 2);    // K permuted-row swizzle
    kSrc[i] = qkv + (size_t)(b * 2048 + row) * 2048 + 1024 + h * 64 + (cp ^ xk) * 8;
    vSrc[i] = vt + (size_t)bh * (64 * 2048) + (size_t)row * 2048 + (cp ^ (row & 7)) * 8;
    kOff[i] = (i * 32 + w * 8) * 64;
    vOff[i] = 4096 + (i * 32 + w * 8) * 64;
  }

  const int kr = (lane15 >> 2) * 8 + (lane15 & 3);   // permuted A-frag key row base
  f32x4 O[4] = {};
  f32x4 sacc = {};
  const u32x4 onesu = {0x3F803F80u, 0x3F803F80u, 0x3F803F80u, 0x3F803F80u};
  const s16x8 onesf = __builtin_bit_cast(s16x8, onesu);

  // prologue: stage tile 0 into buf 0
#pragma unroll
  for (int i = 0; i < 2; ++i) async16(kSrc[i], &S[0][kOff[i]]);
#pragma unroll
  for (int i = 0; i < 2; ++i) async16(vSrc[i], &S[0][vOff[i]]);

  for (int jt = 0; jt < 32; ++jt) {
    __builtin_amdgcn_s_waitcnt(0);   // waits on staging issued one full iter ago
    __syncthreads();
    const u16* Sb = S[jt & 1];
    if (jt < 31) {                   // prefetch next tile into the other buffer
      const size_t kAdv = (size_t)(jt + 1) * 64 * 2048;
      const int vAdv = (jt + 1) * 64;
      u16* D = S[(jt & 1) ^ 1];
#pragma unroll
      for (int i = 0; i < 2; ++i) async16(kSrc[i] + kAdv, D + kOff[i]);
#pragma unroll
      for (int i = 0; i < 2; ++i) async16(vSrc[i] + vAdv, D + vOff[i]);
    }

    // S^T = K Q^T : tile tt row (quad*4+r) -> key quad*8+r +4*(tt&1)+32*(tt>>1)
    f32x4 st[4] = {};
#pragma unroll
    for (int ks2 = 0; ks2 < 2; ++ks2) {
      s16x8 qf = ks2 ? qf1 : qf0;
#pragma unroll
      for (int tt = 0; tt < 4; ++tt) {
        int rr = kr + (tt & 1) * 4 + (tt >> 1) * 32;
        int xk = (rr & 3) | (((rr >> 3) & 1) << 2);
        s16x8 kf = *(const s16x8*)(Sb + rr * 64 + ((ks2 * 4 + quad) ^ xk) * 8);
        st[tt] = __builtin_amdgcn_mfma_f32_16x16x32_bf16(kf, qf, st[tt], 0, 0, 0);
      }
    }

    // per 32-key step: exp2 -> pack -> l-sum MFMA + PV MFMAs
#pragma unroll
    for (int ks = 0; ks < 2; ++ks) {
      float p0 = EXP2(st[2 * ks][0]), p1 = EXP2(st[2 * ks][1]);
      float p2 = EXP2(st[2 * ks][2]), p3 = EXP2(st[2 * ks][3]);
      float p4 = EXP2(st[2 * ks + 1][0]), p5 = EXP2(st[2 * ks + 1][1]);
      float p6 = EXP2(st[2 * ks + 1][2]), p7 = EXP2(st[2 * ks + 1][3]);
      u32x4 pu = {pack2(p0, p1), pack2(p2, p3), pack2(p4, p5), pack2(p6, p7)};
      s16x8 pf = __builtin_bit_cast(s16x8, pu);
      sacc = __builtin_amdgcn_mfma_f32_16x16x32_bf16(onesf, pf, sacc, 0, 0, 0);
      const u16* Vh = Sb + 4096;
      int c7 = ks * 4 + quad;
#pragma unroll
      for (int co = 0; co < 4; ++co) {
        int rr = co * 16 + lane15;
        s16x8 vf = *(const s16x8*)(Vh + rr * 64 + ((c7 ^ (rr & 7))) * 8);
        O[co] = __builtin_amdgcn_mfma_f32_16x16x32_bf16(vf, pf, O[co], 0, 0, 0);
      }
    }
  }

  // l fully summed per q via ones-MFMA: no cross-lane reduction
  float inv = 1.0f / sacc[0];
#pragma unroll
  for (int co = 0; co < 4; ++co) {
    u32x2 o;
    o.x = pack2(O[co][0] * inv, O[co][1] * inv);
    o.y = pack2(O[co][2] * inv, O[co][3] * inv);
    *(u32x2*)(ctx + (size_t)qrow * 1024 + h * 64 + co * 16 + quad * 4) = o;
  }
}

// ---------------- workspace layout (bytes) ----------------
static constexpr size_t OFF_XB  = 0;                        // 16 MB  x bf16 (8192x1024)
static constexpr size_t OFF_WT  = OFF_XB + (16u << 20);     // 6 MB   Wqkv^T bf16 (3072x1024)
static constexpr size_t OFF_WOT = OFF_WT + (6u << 20);      // 2 MB   Wo^T bf16 (1024x1024)
static constexpr size_t OFF_B3  = OFF_WOT + (2u << 20);     // 64 KB  bias3072 fp32
static constexpr size_t OFF_QKV = OFF_B3 + (1u << 20);      // 32 MB  q|k bf16 (8192x2048)
static constexpr size_t OFF_VT  = OFF_QKV + (32u << 20);    // 16 MB  v^T bf16 (B,H,64,2048)
static constexpr size_t OFF_CTX = OFF_VT + (16u << 20);     // 16 MB  ctx bf16 (8192x1024)

extern "C" void kernel_launch(void* const* d_in, const int* in_sizes, int n_in,
                              void* d_out, int out_size, void* d_ws, size_t ws_size,
                              hipStream_t stream) {
  const float* x  = (const float*)d_in[0];
  const float* Wq = (const float*)d_in[1];
  const float* bq = (const float*)d_in[2];
  const float* Wk = (const float*)d_in[3];
  const float* bk = (const float*)d_in[4];
  const float* Wv = (const float*)d_in[5];
  const float* bv = (const float*)d_in[6];
  const float* Wo = (const float*)d_in[7];
  const float* bo = (const float*)d_in[8];
  char* ws = (char*)d_ws;
  u16* xb    = (u16*)(ws + OFF_XB);
  u16* wt    = (u16*)(ws + OFF_WT);
  u16* wot   = (u16*)(ws + OFF_WOT);
  float* b3  = (float*)(ws + OFF_B3);
  u16* qkv   = (u16*)(ws + OFF_QKV);
  u16* vtb   = (u16*)(ws + OFF_VT);
  u16* ctx   = (u16*)(ws + OFF_CTX);
  float* out = (float*)d_out;

  const float QSCALE = 0.125f * 1.44269504f;  // 1/sqrt(64) * log2(e): exp2-domain scores

  k_cast<<<8192, 256, 0, stream>>>(x, xb);
  k_packw_all<<<dim3(32, 32, 4), 256, 0, stream>>>(Wq, Wk, Wv, Wo, wt, wot, QSCALE);
  k_packbias<<<12, 256, 0, stream>>>(bq, bk, bv, b3, QSCALE);
  // Q|K GEMM -> qkv (ldC=2048), coalesced LDS epilogue
  k_gemm_bt<0><<<dim3(64, 16), 256, 0, stream>>>(xb, wt, b3, qkv, nullptr, 1024, 2048, 0);
  // V GEMM -> vtb transposed (B,H,HD,S), coalesced LDS epilogue
  k_gemm_bt<2><<<dim3(64, 8), 256, 0, stream>>>(xb, wt, b3, nullptr, vtb, 1024, 2048, 2048);
  // flash: grid.x = bh (64), grid.y = qt (32)
  k_flash<<<dim3(64, 32), 256, 0, stream>>>(qkv, vtb, ctx);
  // out projection -> fp32 d_out
  k_gemm_bt<1><<<dim3(64, 8), 256, 0, stream>>>(ctx, wot, bo, out, nullptr, 1024, 1024, 0);
}